// Round 12
// baseline (200.509 us; speedup 1.0000x reference)
//
#include <hip/hip_runtime.h>

#define NEG_SLOPE 0.2f
#define CBSH 7            // 128 nodes per coarse bucket
#define MAXNC 512         // max buckets (N <= 65536)

typedef __attribute__((ext_vector_type(8))) short short8;
typedef __attribute__((ext_vector_type(4))) float f32x4;

__device__ __forceinline__ unsigned short f2bf(float f) {
  unsigned u = __float_as_uint(f);
  unsigned r = (u + 0x7FFFu + ((u >> 16) & 1u)) >> 16;
  return (unsigned short)r;
}
__device__ __forceinline__ unsigned pack_bf16(float lo, float hi) {
  return (unsigned)f2bf(lo) | ((unsigned)f2bf(hi) << 16);
}
__device__ __forceinline__ float bflo(unsigned u) {
  return __uint_as_float(u << 16);
}
__device__ __forceinline__ float bfhi(unsigned u) {
  return __uint_as_float(u & 0xFFFF0000u);
}
__device__ __forceinline__ void gload_lds16(const void* g, void* l) {
  __builtin_amdgcn_global_load_lds(
      (const __attribute__((address_space(1))) unsigned*)g,
      (__attribute__((address_space(3))) unsigned*)l, 16, 0, 0);
}

// ---------------------------------------------------------------------------
// W[K][128] fp32 -> Wt[128][K] bf16 (transpose+convert).
// ---------------------------------------------------------------------------
__global__ __launch_bounds__(256) void wconv(const float* __restrict__ W,
                                             unsigned* __restrict__ Wt, int K) {
  int per = K >> 3;
  int t = blockIdx.x * 256 + threadIdx.x;
  if (t >= 128 * per) return;
  int col = t / per;
  int kc = (t - col * per) << 3;
  float w[8];
#pragma unroll
  for (int j = 0; j < 8; ++j) w[j] = W[(size_t)(kc + j) * 128 + col];
  uint4 o = make_uint4(pack_bf16(w[0], w[1]), pack_bf16(w[2], w[3]),
                       pack_bf16(w[4], w[5]), pack_bf16(w[6], w[7]));
  *(uint4*)&Wt[((size_t)col * K + kc) >> 1] = o;
}

// ---------------------------------------------------------------------------
// CSR build, bucket counting-sort (write-combining friendly).
// ---------------------------------------------------------------------------
__global__ __launch_bounds__(256) void ccount(const int* __restrict__ trg,
                                              int* __restrict__ bcnt, int E,
                                              int NC) {
  __shared__ int hist[MAXNC];
  int tid = threadIdx.x;
  for (int i = tid; i < NC; i += 256) hist[i] = 0;
  __syncthreads();
  for (int e = blockIdx.x * 256 + tid; e < E; e += gridDim.x * 256)
    atomicAdd(&hist[trg[e] >> CBSH], 1);
  __syncthreads();
  for (int i = tid; i < NC; i += 256)
    if (hist[i]) atomicAdd(&bcnt[i], hist[i]);
}

__global__ __launch_bounds__(256) void cscan(const int* __restrict__ bcnt,
                                             int* __restrict__ cbase,
                                             int* __restrict__ gcur, int NC) {
  __shared__ int s[MAXNC + 1];
  int tid = threadIdx.x;
  for (int i = tid; i < NC; i += 256) s[i] = bcnt[i];
  __syncthreads();
  if (tid == 0) {
    int run = 0;
    for (int i = 0; i < NC; ++i) {
      int v = s[i];
      s[i] = run;
      run += v;
    }
    s[NC] = run;
  }
  __syncthreads();
  for (int i = tid; i <= NC; i += 256) cbase[i] = s[i];
  for (int i = tid; i < NC; i += 256) gcur[i] = s[i];
}

__global__ __launch_bounds__(256) void cscatter(const int* __restrict__ src,
                                                const int* __restrict__ trg,
                                                int* __restrict__ gcur,
                                                unsigned* __restrict__ EB,
                                                int E, int NC) {
  __shared__ int hist[MAXNC];
  __shared__ int gb[MAXNC];
  __shared__ int lcur[MAXNC];
  __shared__ unsigned lbuf[4096];
  __shared__ unsigned short cb16[4096];
  int tid = threadIdx.x;
  int e0 = blockIdx.x * 4096;
  int cnt = E - e0;
  if (cnt > 4096) cnt = 4096;
  for (int i = tid; i < NC; i += 256) hist[i] = 0;
  __syncthreads();
  unsigned pk[16];
  unsigned short cbr[16];
  int mine = 0;
#pragma unroll
  for (int j = 0; j < 16; ++j) {
    int i = tid + j * 256;
    if (i < cnt) {
      int e = e0 + i;
      int s = src[e];
      int t = trg[e];
      int cb = t >> CBSH;
      pk[j] = ((unsigned)s << CBSH) | (unsigned)(t & ((1 << CBSH) - 1));
      cbr[j] = (unsigned short)cb;
      atomicAdd(&hist[cb], 1);
      mine = j + 1;
    }
  }
  __syncthreads();
  for (int i = tid; i < NC; i += 256)
    gb[i] = hist[i] ? atomicAdd(&gcur[i], hist[i]) : 0;
  __syncthreads();
  if (tid == 0) {
    int run = 0;
    for (int i = 0; i < NC; ++i) {
      int v = hist[i];
      hist[i] = run;
      run += v;
    }
  }
  __syncthreads();
  for (int i = tid; i < NC; i += 256) lcur[i] = hist[i];
  __syncthreads();
  for (int j = 0; j < mine; ++j) {
    int p = atomicAdd(&lcur[cbr[j]], 1);
    lbuf[p] = pk[j];
    cb16[p] = cbr[j];
  }
  __syncthreads();
  for (int i = tid; i < cnt; i += 256) {
    int cb = cb16[i];
    EB[gb[cb] + (i - hist[cb])] = lbuf[i];
  }
}

__global__ __launch_bounds__(256) void bfill(const unsigned* __restrict__ EB,
                                             const int* __restrict__ cbase,
                                             int* __restrict__ rowptr,
                                             int* __restrict__ SS, int N,
                                             int E) {
  __shared__ int deg[128], lofs[128], cur[128];
  int cb = blockIdx.x;
  int b0 = cbase[cb];
  int b1 = cbase[cb + 1];
  int n0 = cb << CBSH;
  int tid = threadIdx.x;
  if (tid < 128) deg[tid] = 0;
  __syncthreads();
  for (int i = b0 + tid; i < b1; i += 256)
    atomicAdd(&deg[EB[i] & ((1 << CBSH) - 1)], 1);
  __syncthreads();
  if (tid == 0) {
    int run = b0;
    for (int l = 0; l < 128; ++l) {
      lofs[l] = run;
      run += deg[l];
    }
  }
  __syncthreads();
  if (tid < 128) {
    cur[tid] = lofs[tid];
    int n = n0 + tid;
    if (n < N) rowptr[n] = lofs[tid];
  }
  if (cb == 0 && tid == 0) rowptr[N] = E;
  __syncthreads();
  for (int i = b0 + tid; i < b1; i += 256) {
    unsigned pk = EB[i];
    int pos = atomicAdd(&cur[pk & ((1 << CBSH) - 1)], 1);
    SS[pos] = (int)(pk >> CBSH);
  }
}

// ---------------------------------------------------------------------------
// Fused dual bf16-MFMA GEMM — round-11 mappings (verified passing), but
// K_STEP=64 single-buffered: per outer step stage TWO 32-k subtiles, then ONE
// expensive drain barrier, 32 MFMAs/matrix, one cheap barrier. Halves the
// vmcnt(0)-drain count (L1: 8->4, L2: 4->2) that dominates the dispatch.
// LDS map (40960 B): A-sub h @ h*4096 (4KB each: chunk w*1024 + lane*16);
// BP-sub h @ 8192+h*8192 (chunk c*1024); BS-sub h @ 24576+h*8192.
// Cs[64][132] epilogue aliases the same region (after barrier).
// mfma 16x16x32_bf16: A row=lane&15,k=(lane>>4)*8+i; B col=lane&15;
// D col=lane&15,row=(lane>>4)*4+reg.
// ---------------------------------------------------------------------------
template <int KK, bool AF32>
__global__ __launch_bounds__(256) void gemm_dual(
    const void* __restrict__ Av, const unsigned* __restrict__ BtP,
    const unsigned* __restrict__ BtS, unsigned* __restrict__ Cb,
    unsigned* __restrict__ PH, const float* __restrict__ a_src,
    const float* __restrict__ a_trg, float* __restrict__ ssrc,
    float* __restrict__ strg, int M) {
  constexpr int NSTEP = KK / 64;
  __shared__ __align__(16) char ldsraw[40960];
  float(*Cs)[132] = (float(*)[132])ldsraw;

  const int tid = threadIdx.x;
  const int lane = tid & 63;
  const int w = tid >> 6;
  const int row0 = blockIdx.x * 64;

  f32x4 accP[8], accS[8];
#pragma unroll
  for (int c = 0; c < 8; ++c) {
    accP[c] = (f32x4)0.f;
    accS[c] = (f32x4)0.f;
  }

  // A staging map (round-11): row arow=tid>>2, k-quarter akq=(tid&3)*8;
  // fragment slot abyte within a 4KB subtile region.
  const int arow = tid >> 2;
  const int akq = (tid & 3) << 3;
  const int agr = row0 + arow;
  const int abyte =
      ((((arow >> 4) << 6) | ((tid & 3) << 4) | (arow & 15)) << 4);
  const unsigned short* BP16 = (const unsigned short*)BtP;
  const unsigned short* BS16 = (const unsigned short*)BtS;
  const int bg = lane >> 4;
  const int br = lane & 15;

  for (int t = 0; t < NSTEP; ++t) {
    const int k0 = t << 6;
    // ---- stage B: both 32-k subtiles, gload_lds direct ----
#pragma unroll
    for (int i = 0; i < 2; ++i) {
      int c = w * 2 + i;
#pragma unroll
      for (int h = 0; h < 2; ++h) {
        size_t eoff = (size_t)(16 * c + br) * KK + k0 + 32 * h + 8 * bg;
        gload_lds16(BP16 + eoff, ldsraw + 8192 + h * 8192 + c * 1024);
        gload_lds16(BS16 + eoff, ldsraw + 24576 + h * 8192 + c * 1024);
      }
    }
    // ---- stage A: both subtiles ----
#pragma unroll
    for (int h = 0; h < 2; ++h) {
      uint4 p;
      if constexpr (AF32) {
        const float* A = (const float*)Av;
        float4 v0 = make_float4(0.f, 0.f, 0.f, 0.f), v1 = v0;
        if (agr < M) {
          v0 = *(const float4*)&A[(size_t)agr * KK + k0 + 32 * h + akq];
          v1 = *(const float4*)&A[(size_t)agr * KK + k0 + 32 * h + akq + 4];
        }
        p = make_uint4(pack_bf16(v0.x, v0.y), pack_bf16(v0.z, v0.w),
                       pack_bf16(v1.x, v1.y), pack_bf16(v1.z, v1.w));
      } else {
        const unsigned short* A = (const unsigned short*)Av;
        p = make_uint4(0u, 0u, 0u, 0u);
        if (agr < M)
          p = *(const uint4*)&A[(size_t)agr * KK + k0 + 32 * h + akq];
      }
      *(uint4*)(ldsraw + h * 4096 + abyte) = p;
    }
    __syncthreads();  // expensive drain: 1 per 64-k (was 1 per 32-k)
    // ---- 32 MFMAs per matrix over both subtiles ----
#pragma unroll
    for (int h = 0; h < 2; ++h) {
      short8 af = *(const short8*)(ldsraw + h * 4096 + w * 1024 + lane * 16);
#pragma unroll
      for (int c = 0; c < 8; ++c) {
        short8 bp = *(const short8*)(ldsraw + 8192 + h * 8192 + c * 1024 +
                                     lane * 16);
        accP[c] =
            __builtin_amdgcn_mfma_f32_16x16x32_bf16(af, bp, accP[c], 0, 0, 0);
        short8 bs = *(const short8*)(ldsraw + 24576 + h * 8192 + c * 1024 +
                                     lane * 16);
        accS[c] =
            __builtin_amdgcn_mfma_f32_16x16x32_bf16(af, bs, accS[c], 0, 0, 0);
      }
    }
    __syncthreads();  // cheap barrier (no vm ops outstanding)
  }

  const int hrow = lane >> 5;
  const int c32 = lane & 31;

  // ---- proj epilogue: PH (bf16) + fused scores ----
#pragma unroll
  for (int c = 0; c < 8; ++c)
#pragma unroll
    for (int r = 0; r < 4; ++r)
      Cs[16 * w + ((lane >> 4) << 2) + r][16 * c + (lane & 15)] = accP[c][r];
  __syncthreads();
#pragma unroll
  for (int i = 0; i < 8; ++i) {
    int lr = 16 * w + 2 * i + hrow;
    int gr = row0 + lr;
    if (gr < M) {
      float4 v = *(const float4*)&Cs[lr][c32 * 4];
      *(uint2*)&PH[(size_t)gr * 64 + c32 * 2] =
          make_uint2(pack_bf16(v.x, v.y), pack_bf16(v.z, v.w));
    }
  }
  {
    int srow = tid >> 2;
    int q = tid & 3;
    int gr = row0 + srow;
    float ds = 0.f, dt = 0.f;
#pragma unroll
    for (int j = 0; j < 8; ++j) {
      int col = q * 32 + j * 4;
      float4 v = *(const float4*)&Cs[srow][col];
      float4 asv = *(const float4*)&a_src[col];
      float4 atv = *(const float4*)&a_trg[col];
      ds += v.x * asv.x + v.y * asv.y + v.z * asv.z + v.w * asv.w;
      dt += v.x * atv.x + v.y * atv.y + v.z * atv.z + v.w * atv.w;
    }
    ds += __shfl_xor(ds, 1, 64);
    dt += __shfl_xor(dt, 1, 64);
    if (gr < M && (q & 1) == 0) {
      int h = q >> 1;
      ssrc[gr * 2 + h] = ds;
      strg[gr * 2 + h] = dt;
    }
  }
  __syncthreads();

  // ---- skip epilogue: Cb (packed bf16) ----
#pragma unroll
  for (int c = 0; c < 8; ++c)
#pragma unroll
    for (int r = 0; r < 4; ++r)
      Cs[16 * w + ((lane >> 4) << 2) + r][16 * c + (lane & 15)] = accS[c][r];
  __syncthreads();
#pragma unroll
  for (int i = 0; i < 8; ++i) {
    int lr = 16 * w + 2 * i + hrow;
    int gr = row0 + lr;
    if (gr < M) {
      float4 v = *(const float4*)&Cs[lr][c32 * 4];
      *(uint2*)&Cb[(size_t)gr * 64 + c32 * 2] =
          make_uint2(pack_bf16(v.x, v.y), pack_bf16(v.z, v.w));
    }
  }
}

// ---------------------------------------------------------------------------
// Fused aggregation: one wave per node; weights recomputed on the fly; bf16
// messages from PH; bf16 skip from Sb; readlane-broadcast indices; 4 edges in
// flight. LAYER==1: out = packed-bf16 relu(agg+skip+b) -> (N,64 uints).
// LAYER==2: out = fp32 head-mean (N,64).
// ---------------------------------------------------------------------------
template <int LAYER>
__global__ __launch_bounds__(256) void aggregate(
    const int* __restrict__ rowptr, const int* __restrict__ SS,
    const float2* __restrict__ ssrc, const float2* __restrict__ strg,
    const unsigned* __restrict__ PH, const unsigned* __restrict__ Sb,
    const float* __restrict__ bias, void* __restrict__ Outv, int Nn) {
  int wid = (int)((blockIdx.x * blockDim.x + threadIdx.x) >> 6);
  int lane = threadIdx.x & 63;
  if (wid >= Nn) return;
  int n = wid;
  bool hi = lane >= 32;
  float2 st = strg[n];
  float et = hi ? st.y : st.x;
  int beg = rowptr[n];
  int end = rowptr[n + 1];
  float accx = 0.f, accy = 0.f, dsum = 0.f;

  for (int base = beg; base < end; base += 64) {
    int cnt = end - base;
    if (cnt > 64) cnt = 64;
    int idx = base + lane;
    int sv = (idx < end) ? SS[idx] : 0;
    int j = 0;
    for (; j + 4 <= cnt; j += 4) {
      int s0 = __builtin_amdgcn_readlane(sv, j + 0);
      int s1 = __builtin_amdgcn_readlane(sv, j + 1);
      int s2 = __builtin_amdgcn_readlane(sv, j + 2);
      int s3 = __builtin_amdgcn_readlane(sv, j + 3);
      unsigned w0 = PH[(size_t)s0 * 64 + lane];
      unsigned w1 = PH[(size_t)s1 * 64 + lane];
      unsigned w2 = PH[(size_t)s2 * 64 + lane];
      unsigned w3 = PH[(size_t)s3 * 64 + lane];
      float2 e0 = ssrc[s0];
      float2 e1 = ssrc[s1];
      float2 e2 = ssrc[s2];
      float2 e3 = ssrc[s3];
      float z0 = (hi ? e0.y : e0.x) + et;
      float z1 = (hi ? e1.y : e1.x) + et;
      float z2 = (hi ? e2.y : e2.x) + et;
      float z3 = (hi ? e3.y : e3.x) + et;
      z0 = (z0 >= 0.f) ? z0 : NEG_SLOPE * z0;
      z1 = (z1 >= 0.f) ? z1 : NEG_SLOPE * z1;
      z2 = (z2 >= 0.f) ? z2 : NEG_SLOPE * z2;
      z3 = (z3 >= 0.f) ? z3 : NEG_SLOPE * z3;
      float g0 = __expf(z0), g1 = __expf(z1), g2 = __expf(z2), g3 = __expf(z3);
      dsum += (g0 + g1) + (g2 + g3);
      accx = fmaf(bflo(w0), g0, accx);
      accy = fmaf(bfhi(w0), g0, accy);
      accx = fmaf(bflo(w1), g1, accx);
      accy = fmaf(bfhi(w1), g1, accy);
      accx = fmaf(bflo(w2), g2, accx);
      accy = fmaf(bfhi(w2), g2, accy);
      accx = fmaf(bflo(w3), g3, accx);
      accy = fmaf(bfhi(w3), g3, accy);
    }
    for (; j < cnt; ++j) {
      int s0 = __builtin_amdgcn_readlane(sv, j);
      unsigned w0 = PH[(size_t)s0 * 64 + lane];
      float2 e0 = ssrc[s0];
      float z0 = (hi ? e0.y : e0.x) + et;
      z0 = (z0 >= 0.f) ? z0 : NEG_SLOPE * z0;
      float g0 = __expf(z0);
      dsum += g0;
      accx = fmaf(bflo(w0), g0, accx);
      accy = fmaf(bfhi(w0), g0, accy);
    }
  }

  float inv = 1.0f / (dsum + 1e-16f);
  accx *= inv;
  accy *= inv;
  unsigned skv = Sb[(size_t)n * 64 + lane];
  float skx = bflo(skv);
  float sky = bfhi(skv);
  if (LAYER == 1) {
    float2 b = *(const float2*)&bias[lane * 2];
    float zx = fmaxf(accx + skx + b.x, 0.f);
    float zy = fmaxf(accy + sky + b.y, 0.f);
    ((unsigned*)Outv)[(size_t)n * 64 + lane] = pack_bf16(zx, zy);
  } else {
    float zx = accx + skx;
    float zy = accy + sky;
    float ox = __shfl(zx, lane + 32, 64);
    float oy = __shfl(zy, lane + 32, 64);
    if (lane < 32) {
      float2 b = *(const float2*)&bias[lane * 2];
      float rx = 0.5f * (zx + ox) + b.x;
      float ry = 0.5f * (zy + oy) + b.y;
      *(float2*)&((float*)Outv)[(size_t)n * 64 + lane * 2] =
          make_float2(rx, ry);
    }
  }
}

// ---------------------------------------------------------------------------
extern "C" void kernel_launch(void* const* d_in, const int* in_sizes, int n_in,
                              void* d_out, int out_size, void* d_ws,
                              size_t ws_size, hipStream_t stream) {
  const float* x = (const float*)d_in[0];
  const int* ei = (const int*)d_in[1];
  const float* W0 = (const float*)d_in[2];
  const float* a_src0 = (const float*)d_in[3];
  const float* a_trg0 = (const float*)d_in[4];
  const float* Wsk0 = (const float*)d_in[5];
  const float* b0 = (const float*)d_in[6];
  const float* W2 = (const float*)d_in[7];
  const float* a_src2 = (const float*)d_in[8];
  const float* a_trg2 = (const float*)d_in[9];
  const float* Wsk2 = (const float*)d_in[10];
  const float* b2 = (const float*)d_in[11];

  const int FIN = 256;
  const int N = in_sizes[0] / FIN;
  const int E = in_sizes[1] / 2;
  const int* src = ei;
  const int* trg = ei + E;
  const int NC = (N + (1 << CBSH) - 1) >> CBSH;

  char* base = (char*)d_ws;
  size_t off = 0;
  auto alloc = [&](size_t bytes) -> void* {
    void* p = base + off;
    off += (bytes + 255) & ~(size_t)255;
    return p;
  };
  unsigned* PH = (unsigned*)alloc((size_t)N * 64 * sizeof(unsigned));
  unsigned* Sb = (unsigned*)alloc((size_t)N * 64 * sizeof(unsigned));
  unsigned* Hb = (unsigned*)alloc((size_t)N * 64 * sizeof(unsigned));
  int* SS = (int*)alloc((size_t)E * sizeof(int));
  unsigned* EB = (unsigned*)alloc((size_t)E * sizeof(unsigned));
  float* ssrc = (float*)alloc((size_t)N * 2 * sizeof(float));
  float* strg = (float*)alloc((size_t)N * 2 * sizeof(float));
  int* rowptr = (int*)alloc((size_t)(N + 1) * sizeof(int));
  int* bcnt = (int*)alloc((size_t)MAXNC * sizeof(int));
  int* cbase = (int*)alloc((size_t)(MAXNC + 1) * sizeof(int));
  int* gcur = (int*)alloc((size_t)MAXNC * sizeof(int));
  unsigned* WtP0 = (unsigned*)alloc((size_t)128 * 256 * 2);
  unsigned* WtS0 = (unsigned*)alloc((size_t)128 * 256 * 2);
  unsigned* WtP2 = (unsigned*)alloc((size_t)128 * 128 * 2);
  unsigned* WtS2 = (unsigned*)alloc((size_t)128 * 128 * 2);

  hipMemsetAsync(bcnt, 0, (size_t)MAXNC * sizeof(int), stream);

  dim3 blk(256);
  int gemmBlocks = (N + 63) / 64;
  int nodeBlocks = (N + 3) / 4;
  int chunkBlocks = (E + 4095) / 4096;

  // ---- weight prep ----
  wconv<<<16, blk, 0, stream>>>(W0, WtP0, 256);
  wconv<<<16, blk, 0, stream>>>(Wsk0, WtS0, 256);
  wconv<<<8, blk, 0, stream>>>(W2, WtP2, 128);
  wconv<<<8, blk, 0, stream>>>(Wsk2, WtS2, 128);

  // ---- CSR build (bucket counting sort) ----
  ccount<<<256, blk, 0, stream>>>(trg, bcnt, E, NC);
  cscan<<<1, blk, 0, stream>>>(bcnt, cbase, gcur, NC);
  cscatter<<<chunkBlocks, blk, 0, stream>>>(src, trg, gcur, EB, E, NC);
  bfill<<<NC, blk, 0, stream>>>(EB, cbase, rowptr, SS, N, E);

  // ---- layer 1 ----
  gemm_dual<256, true><<<gemmBlocks, blk, 0, stream>>>(
      x, WtP0, WtS0, Sb, PH, a_src0, a_trg0, ssrc, strg, N);
  aggregate<1><<<nodeBlocks, blk, 0, stream>>>(rowptr, SS, (const float2*)ssrc,
                                               (const float2*)strg, PH, Sb, b0,
                                               Hb, N);
  // ---- layer 2 (h lives in Hb, bf16) ----
  gemm_dual<128, false><<<gemmBlocks, blk, 0, stream>>>(
      Hb, WtP2, WtS2, Sb, PH, a_src2, a_trg2, ssrc, strg, N);
  aggregate<2><<<nodeBlocks, blk, 0, stream>>>(rowptr, SS, (const float2*)ssrc,
                                               (const float2*)strg, PH, Sb, b2,
                                               d_out, N);
}

// Round 13
// 182.320 us; speedup vs baseline: 1.0998x; 1.0998x over previous
//
#include <hip/hip_runtime.h>

#define NEG_SLOPE 0.2f
#define CBSH 7            // 128 nodes per coarse bucket
#define MAXNC 512         // max buckets (N <= 65536)

typedef __attribute__((ext_vector_type(8))) short short8;
typedef __attribute__((ext_vector_type(4))) float f32x4;

__device__ __forceinline__ unsigned short f2bf(float f) {
  unsigned u = __float_as_uint(f);
  unsigned r = (u + 0x7FFFu + ((u >> 16) & 1u)) >> 16;
  return (unsigned short)r;
}
__device__ __forceinline__ unsigned pack_bf16(float lo, float hi) {
  return (unsigned)f2bf(lo) | ((unsigned)f2bf(hi) << 16);
}
__device__ __forceinline__ float bflo(unsigned u) {
  return __uint_as_float(u << 16);
}
__device__ __forceinline__ float bfhi(unsigned u) {
  return __uint_as_float(u & 0xFFFF0000u);
}
__device__ __forceinline__ void gload_lds16(const void* g, void* l) {
  __builtin_amdgcn_global_load_lds(
      (const __attribute__((address_space(1))) unsigned*)g,
      (__attribute__((address_space(3))) unsigned*)l, 16, 0, 0);
}

// ---------------------------------------------------------------------------
// W[K][128] fp32 -> Wt[128][K] bf16 (transpose+convert).
// ---------------------------------------------------------------------------
__global__ __launch_bounds__(256) void wconv(const float* __restrict__ W,
                                             unsigned* __restrict__ Wt, int K) {
  int per = K >> 3;
  int t = blockIdx.x * 256 + threadIdx.x;
  if (t >= 128 * per) return;
  int col = t / per;
  int kc = (t - col * per) << 3;
  float w[8];
#pragma unroll
  for (int j = 0; j < 8; ++j) w[j] = W[(size_t)(kc + j) * 128 + col];
  uint4 o = make_uint4(pack_bf16(w[0], w[1]), pack_bf16(w[2], w[3]),
                       pack_bf16(w[4], w[5]), pack_bf16(w[6], w[7]));
  *(uint4*)&Wt[((size_t)col * K + kc) >> 1] = o;
}

// ---------------------------------------------------------------------------
// CSR build, bucket counting-sort (write-combining friendly).
// ---------------------------------------------------------------------------
__global__ __launch_bounds__(256) void ccount(const int* __restrict__ trg,
                                              int* __restrict__ bcnt, int E,
                                              int NC) {
  __shared__ int hist[MAXNC];
  int tid = threadIdx.x;
  for (int i = tid; i < NC; i += 256) hist[i] = 0;
  __syncthreads();
  for (int e = blockIdx.x * 256 + tid; e < E; e += gridDim.x * 256)
    atomicAdd(&hist[trg[e] >> CBSH], 1);
  __syncthreads();
  for (int i = tid; i < NC; i += 256)
    if (hist[i]) atomicAdd(&bcnt[i], hist[i]);
}

__global__ __launch_bounds__(256) void cscan(const int* __restrict__ bcnt,
                                             int* __restrict__ cbase,
                                             int* __restrict__ gcur, int NC) {
  __shared__ int s[MAXNC + 1];
  int tid = threadIdx.x;
  for (int i = tid; i < NC; i += 256) s[i] = bcnt[i];
  __syncthreads();
  if (tid == 0) {
    int run = 0;
    for (int i = 0; i < NC; ++i) {
      int v = s[i];
      s[i] = run;
      run += v;
    }
    s[NC] = run;
  }
  __syncthreads();
  for (int i = tid; i <= NC; i += 256) cbase[i] = s[i];
  for (int i = tid; i < NC; i += 256) gcur[i] = s[i];
}

__global__ __launch_bounds__(256) void cscatter(const int* __restrict__ src,
                                                const int* __restrict__ trg,
                                                int* __restrict__ gcur,
                                                unsigned* __restrict__ EB,
                                                int E, int NC) {
  __shared__ int hist[MAXNC];
  __shared__ int gb[MAXNC];
  __shared__ int lcur[MAXNC];
  __shared__ unsigned lbuf[4096];
  __shared__ unsigned short cb16[4096];
  int tid = threadIdx.x;
  int e0 = blockIdx.x * 4096;
  int cnt = E - e0;
  if (cnt > 4096) cnt = 4096;
  for (int i = tid; i < NC; i += 256) hist[i] = 0;
  __syncthreads();
  unsigned pk[16];
  unsigned short cbr[16];
  int mine = 0;
#pragma unroll
  for (int j = 0; j < 16; ++j) {
    int i = tid + j * 256;
    if (i < cnt) {
      int e = e0 + i;
      int s = src[e];
      int t = trg[e];
      int cb = t >> CBSH;
      pk[j] = ((unsigned)s << CBSH) | (unsigned)(t & ((1 << CBSH) - 1));
      cbr[j] = (unsigned short)cb;
      atomicAdd(&hist[cb], 1);
      mine = j + 1;
    }
  }
  __syncthreads();
  for (int i = tid; i < NC; i += 256)
    gb[i] = hist[i] ? atomicAdd(&gcur[i], hist[i]) : 0;
  __syncthreads();
  if (tid == 0) {
    int run = 0;
    for (int i = 0; i < NC; ++i) {
      int v = hist[i];
      hist[i] = run;
      run += v;
    }
  }
  __syncthreads();
  for (int i = tid; i < NC; i += 256) lcur[i] = hist[i];
  __syncthreads();
  for (int j = 0; j < mine; ++j) {
    int p = atomicAdd(&lcur[cbr[j]], 1);
    lbuf[p] = pk[j];
    cb16[p] = cbr[j];
  }
  __syncthreads();
  for (int i = tid; i < cnt; i += 256) {
    int cb = cb16[i];
    EB[gb[cb] + (i - hist[cb])] = lbuf[i];
  }
}

__global__ __launch_bounds__(256) void bfill(const unsigned* __restrict__ EB,
                                             const int* __restrict__ cbase,
                                             int* __restrict__ rowptr,
                                             int* __restrict__ SS, int N,
                                             int E) {
  __shared__ int deg[128], lofs[128], cur[128];
  int cb = blockIdx.x;
  int b0 = cbase[cb];
  int b1 = cbase[cb + 1];
  int n0 = cb << CBSH;
  int tid = threadIdx.x;
  if (tid < 128) deg[tid] = 0;
  __syncthreads();
  for (int i = b0 + tid; i < b1; i += 256)
    atomicAdd(&deg[EB[i] & ((1 << CBSH) - 1)], 1);
  __syncthreads();
  if (tid == 0) {
    int run = b0;
    for (int l = 0; l < 128; ++l) {
      lofs[l] = run;
      run += deg[l];
    }
  }
  __syncthreads();
  if (tid < 128) {
    cur[tid] = lofs[tid];
    int n = n0 + tid;
    if (n < N) rowptr[n] = lofs[tid];
  }
  if (cb == 0 && tid == 0) rowptr[N] = E;
  __syncthreads();
  for (int i = b0 + tid; i < b1; i += 256) {
    unsigned pk = EB[i];
    int pos = atomicAdd(&cur[pk & ((1 << CBSH) - 1)], 1);
    SS[pos] = (int)(pk >> CBSH);
  }
}

// ---------------------------------------------------------------------------
// Fused dual bf16-MFMA GEMM — 128-row tile, 8 waves (512 thr), K_STEP=32
// (round-11 proven inner loop & mappings). Per-wave per-step work identical
// to the 64-row version (16 MFMAs, 1 gload_lds per matrix), but block count
// halves and B traffic halves -> fixed overhead amortized over 2x rows.
// LDS (33792 B): A-frags 8KB @0 (chunk w*1024 + lane*16), BP 8KB @8192,
// BS 8KB @16384; epilogue Cs[64][132] aliases everything, run in two
// 64-row halves (waves 0-3 then 4-7).
// mfma 16x16x32_bf16: A row=lane&15,k=(lane>>4)*8+i; B col=lane&15;
// D col=lane&15,row=(lane>>4)*4+reg.
// ---------------------------------------------------------------------------
template <int KK, bool AF32>
__global__ __launch_bounds__(512) void gemm_dual(
    const void* __restrict__ Av, const unsigned* __restrict__ BtP,
    const unsigned* __restrict__ BtS, unsigned* __restrict__ Cb,
    unsigned* __restrict__ PH, const float* __restrict__ a_src,
    const float* __restrict__ a_trg, float* __restrict__ ssrc,
    float* __restrict__ strg, int M) {
  constexpr int NSTEP = KK / 32;
  __shared__ __align__(16) char ldsraw[33792];
  float(*Cs)[132] = (float(*)[132])ldsraw;

  const int tid = threadIdx.x;
  const int lane = tid & 63;
  const int w = tid >> 6;  // 0..7
  const int row0 = blockIdx.x * 128;

  f32x4 accP[8], accS[8];
#pragma unroll
  for (int c = 0; c < 8; ++c) {
    accP[c] = (f32x4)0.f;
    accS[c] = (f32x4)0.f;
  }

  // A staging map: row arow=tid>>2 (0..127), k-quarter akq=(tid&3)*8;
  // fragment slot abyte in the 8KB A region (chunk = arow>>4 == wave).
  const int arow = tid >> 2;
  const int akq = (tid & 3) << 3;
  const int agr = row0 + arow;
  const int abyte =
      ((((arow >> 4) << 6) | ((tid & 3) << 4) | (arow & 15)) << 4);
  const unsigned short* BP16 = (const unsigned short*)BtP;
  const unsigned short* BS16 = (const unsigned short*)BtS;
  const int bg = lane >> 4;
  const int br = lane & 15;

  for (int t = 0; t < NSTEP; ++t) {
    const int k0 = t << 5;
    // ---- stage B: wave w covers col-frag c=w for both matrices ----
    {
      size_t eoff = (size_t)(16 * w + br) * KK + k0 + 8 * bg;
      gload_lds16(BP16 + eoff, ldsraw + 8192 + w * 1024);
      gload_lds16(BS16 + eoff, ldsraw + 16384 + w * 1024);
    }
    // ---- stage A ----
    {
      uint4 p;
      if constexpr (AF32) {
        const float* A = (const float*)Av;
        float4 v0 = make_float4(0.f, 0.f, 0.f, 0.f), v1 = v0;
        if (agr < M) {
          v0 = *(const float4*)&A[(size_t)agr * KK + k0 + akq];
          v1 = *(const float4*)&A[(size_t)agr * KK + k0 + akq + 4];
        }
        p = make_uint4(pack_bf16(v0.x, v0.y), pack_bf16(v0.z, v0.w),
                       pack_bf16(v1.x, v1.y), pack_bf16(v1.z, v1.w));
      } else {
        const unsigned short* A = (const unsigned short*)Av;
        p = make_uint4(0u, 0u, 0u, 0u);
        if (agr < M) p = *(const uint4*)&A[(size_t)agr * KK + k0 + akq];
      }
      *(uint4*)(ldsraw + abyte) = p;
    }
    __syncthreads();
    // ---- MFMA: wave w's rows x 8 col-frags x 2 matrices ----
    short8 af = *(const short8*)(ldsraw + w * 1024 + lane * 16);
#pragma unroll
    for (int c = 0; c < 8; ++c) {
      short8 bp = *(const short8*)(ldsraw + 8192 + c * 1024 + lane * 16);
      accP[c] =
          __builtin_amdgcn_mfma_f32_16x16x32_bf16(af, bp, accP[c], 0, 0, 0);
      short8 bs = *(const short8*)(ldsraw + 16384 + c * 1024 + lane * 16);
      accS[c] =
          __builtin_amdgcn_mfma_f32_16x16x32_bf16(af, bs, accS[c], 0, 0, 0);
    }
    __syncthreads();
  }

  const int hrow = lane >> 5;
  const int c32 = lane & 31;
  const int wh = w >> 2;   // which 64-row half this wave belongs to
  const int w4 = w & 3;    // wave index within the half

  // ---- proj epilogue (two 64-row halves): PH (bf16) + fused scores ----
#pragma unroll
  for (int h = 0; h < 2; ++h) {
    if (wh == h) {
#pragma unroll
      for (int c = 0; c < 8; ++c)
#pragma unroll
        for (int r = 0; r < 4; ++r)
          Cs[16 * w4 + ((lane >> 4) << 2) + r][16 * c + (lane & 15)] =
              accP[c][r];
    }
    __syncthreads();
    if (wh == h) {
#pragma unroll
      for (int i = 0; i < 8; ++i) {
        int lr = 16 * w4 + 2 * i + hrow;
        int gr = row0 + 64 * h + lr;
        if (gr < M) {
          float4 v = *(const float4*)&Cs[lr][c32 * 4];
          *(uint2*)&PH[(size_t)gr * 64 + c32 * 2] =
              make_uint2(pack_bf16(v.x, v.y), pack_bf16(v.z, v.w));
        }
      }
      int tid4 = tid - h * 256;  // 0..255 within the participating half
      int srow = tid4 >> 2;
      int q = tid4 & 3;
      int gr = row0 + 64 * h + srow;
      float ds = 0.f, dt = 0.f;
#pragma unroll
      for (int j = 0; j < 8; ++j) {
        int col = q * 32 + j * 4;
        float4 v = *(const float4*)&Cs[srow][col];
        float4 asv = *(const float4*)&a_src[col];
        float4 atv = *(const float4*)&a_trg[col];
        ds += v.x * asv.x + v.y * asv.y + v.z * asv.z + v.w * asv.w;
        dt += v.x * atv.x + v.y * atv.y + v.z * atv.z + v.w * atv.w;
      }
      ds += __shfl_xor(ds, 1, 64);
      dt += __shfl_xor(dt, 1, 64);
      if (gr < M && (q & 1) == 0) {
        int hh = q >> 1;
        ssrc[gr * 2 + hh] = ds;
        strg[gr * 2 + hh] = dt;
      }
    }
    __syncthreads();
  }

  // ---- skip epilogue (two halves): Cb (packed bf16) ----
#pragma unroll
  for (int h = 0; h < 2; ++h) {
    if (wh == h) {
#pragma unroll
      for (int c = 0; c < 8; ++c)
#pragma unroll
        for (int r = 0; r < 4; ++r)
          Cs[16 * w4 + ((lane >> 4) << 2) + r][16 * c + (lane & 15)] =
              accS[c][r];
    }
    __syncthreads();
    if (wh == h) {
#pragma unroll
      for (int i = 0; i < 8; ++i) {
        int lr = 16 * w4 + 2 * i + hrow;
        int gr = row0 + 64 * h + lr;
        if (gr < M) {
          float4 v = *(const float4*)&Cs[lr][c32 * 4];
          *(uint2*)&Cb[(size_t)gr * 64 + c32 * 2] =
              make_uint2(pack_bf16(v.x, v.y), pack_bf16(v.z, v.w));
        }
      }
    }
    __syncthreads();
  }
}

// ---------------------------------------------------------------------------
// Fused aggregation: one wave per node; weights recomputed on the fly; bf16
// messages from PH; bf16 skip from Sb; readlane-broadcast indices; 4 edges in
// flight. LAYER==1: out = packed-bf16 relu(agg+skip+b) -> (N,64 uints).
// LAYER==2: out = fp32 head-mean (N,64).
// ---------------------------------------------------------------------------
template <int LAYER>
__global__ __launch_bounds__(256) void aggregate(
    const int* __restrict__ rowptr, const int* __restrict__ SS,
    const float2* __restrict__ ssrc, const float2* __restrict__ strg,
    const unsigned* __restrict__ PH, const unsigned* __restrict__ Sb,
    const float* __restrict__ bias, void* __restrict__ Outv, int Nn) {
  int wid = (int)((blockIdx.x * blockDim.x + threadIdx.x) >> 6);
  int lane = threadIdx.x & 63;
  if (wid >= Nn) return;
  int n = wid;
  bool hi = lane >= 32;
  float2 st = strg[n];
  float et = hi ? st.y : st.x;
  int beg = rowptr[n];
  int end = rowptr[n + 1];
  float accx = 0.f, accy = 0.f, dsum = 0.f;

  for (int base = beg; base < end; base += 64) {
    int cnt = end - base;
    if (cnt > 64) cnt = 64;
    int idx = base + lane;
    int sv = (idx < end) ? SS[idx] : 0;
    int j = 0;
    for (; j + 4 <= cnt; j += 4) {
      int s0 = __builtin_amdgcn_readlane(sv, j + 0);
      int s1 = __builtin_amdgcn_readlane(sv, j + 1);
      int s2 = __builtin_amdgcn_readlane(sv, j + 2);
      int s3 = __builtin_amdgcn_readlane(sv, j + 3);
      unsigned w0 = PH[(size_t)s0 * 64 + lane];
      unsigned w1 = PH[(size_t)s1 * 64 + lane];
      unsigned w2 = PH[(size_t)s2 * 64 + lane];
      unsigned w3 = PH[(size_t)s3 * 64 + lane];
      float2 e0 = ssrc[s0];
      float2 e1 = ssrc[s1];
      float2 e2 = ssrc[s2];
      float2 e3 = ssrc[s3];
      float z0 = (hi ? e0.y : e0.x) + et;
      float z1 = (hi ? e1.y : e1.x) + et;
      float z2 = (hi ? e2.y : e2.x) + et;
      float z3 = (hi ? e3.y : e3.x) + et;
      z0 = (z0 >= 0.f) ? z0 : NEG_SLOPE * z0;
      z1 = (z1 >= 0.f) ? z1 : NEG_SLOPE * z1;
      z2 = (z2 >= 0.f) ? z2 : NEG_SLOPE * z2;
      z3 = (z3 >= 0.f) ? z3 : NEG_SLOPE * z3;
      float g0 = __expf(z0), g1 = __expf(z1), g2 = __expf(z2), g3 = __expf(z3);
      dsum += (g0 + g1) + (g2 + g3);
      accx = fmaf(bflo(w0), g0, accx);
      accy = fmaf(bfhi(w0), g0, accy);
      accx = fmaf(bflo(w1), g1, accx);
      accy = fmaf(bfhi(w1), g1, accy);
      accx = fmaf(bflo(w2), g2, accx);
      accy = fmaf(bfhi(w2), g2, accy);
      accx = fmaf(bflo(w3), g3, accx);
      accy = fmaf(bfhi(w3), g3, accy);
    }
    for (; j < cnt; ++j) {
      int s0 = __builtin_amdgcn_readlane(sv, j);
      unsigned w0 = PH[(size_t)s0 * 64 + lane];
      float2 e0 = ssrc[s0];
      float z0 = (hi ? e0.y : e0.x) + et;
      z0 = (z0 >= 0.f) ? z0 : NEG_SLOPE * z0;
      float g0 = __expf(z0);
      dsum += g0;
      accx = fmaf(bflo(w0), g0, accx);
      accy = fmaf(bfhi(w0), g0, accy);
    }
  }

  float inv = 1.0f / (dsum + 1e-16f);
  accx *= inv;
  accy *= inv;
  unsigned skv = Sb[(size_t)n * 64 + lane];
  float skx = bflo(skv);
  float sky = bfhi(skv);
  if (LAYER == 1) {
    float2 b = *(const float2*)&bias[lane * 2];
    float zx = fmaxf(accx + skx + b.x, 0.f);
    float zy = fmaxf(accy + sky + b.y, 0.f);
    ((unsigned*)Outv)[(size_t)n * 64 + lane] = pack_bf16(zx, zy);
  } else {
    float zx = accx + skx;
    float zy = accy + sky;
    float ox = __shfl(zx, lane + 32, 64);
    float oy = __shfl(zy, lane + 32, 64);
    if (lane < 32) {
      float2 b = *(const float2*)&bias[lane * 2];
      float rx = 0.5f * (zx + ox) + b.x;
      float ry = 0.5f * (zy + oy) + b.y;
      *(float2*)&((float*)Outv)[(size_t)n * 64 + lane * 2] =
          make_float2(rx, ry);
    }
  }
}

// ---------------------------------------------------------------------------
extern "C" void kernel_launch(void* const* d_in, const int* in_sizes, int n_in,
                              void* d_out, int out_size, void* d_ws,
                              size_t ws_size, hipStream_t stream) {
  const float* x = (const float*)d_in[0];
  const int* ei = (const int*)d_in[1];
  const float* W0 = (const float*)d_in[2];
  const float* a_src0 = (const float*)d_in[3];
  const float* a_trg0 = (const float*)d_in[4];
  const float* Wsk0 = (const float*)d_in[5];
  const float* b0 = (const float*)d_in[6];
  const float* W2 = (const float*)d_in[7];
  const float* a_src2 = (const float*)d_in[8];
  const float* a_trg2 = (const float*)d_in[9];
  const float* Wsk2 = (const float*)d_in[10];
  const float* b2 = (const float*)d_in[11];

  const int FIN = 256;
  const int N = in_sizes[0] / FIN;
  const int E = in_sizes[1] / 2;
  const int* src = ei;
  const int* trg = ei + E;
  const int NC = (N + (1 << CBSH) - 1) >> CBSH;

  char* base = (char*)d_ws;
  size_t off = 0;
  auto alloc = [&](size_t bytes) -> void* {
    void* p = base + off;
    off += (bytes + 255) & ~(size_t)255;
    return p;
  };
  unsigned* PH = (unsigned*)alloc((size_t)N * 64 * sizeof(unsigned));
  unsigned* Sb = (unsigned*)alloc((size_t)N * 64 * sizeof(unsigned));
  unsigned* Hb = (unsigned*)alloc((size_t)N * 64 * sizeof(unsigned));
  int* SS = (int*)alloc((size_t)E * sizeof(int));
  unsigned* EB = (unsigned*)alloc((size_t)E * sizeof(unsigned));
  float* ssrc = (float*)alloc((size_t)N * 2 * sizeof(float));
  float* strg = (float*)alloc((size_t)N * 2 * sizeof(float));
  int* rowptr = (int*)alloc((size_t)(N + 1) * sizeof(int));
  int* bcnt = (int*)alloc((size_t)MAXNC * sizeof(int));
  int* cbase = (int*)alloc((size_t)(MAXNC + 1) * sizeof(int));
  int* gcur = (int*)alloc((size_t)MAXNC * sizeof(int));
  unsigned* WtP0 = (unsigned*)alloc((size_t)128 * 256 * 2);
  unsigned* WtS0 = (unsigned*)alloc((size_t)128 * 256 * 2);
  unsigned* WtP2 = (unsigned*)alloc((size_t)128 * 128 * 2);
  unsigned* WtS2 = (unsigned*)alloc((size_t)128 * 128 * 2);

  hipMemsetAsync(bcnt, 0, (size_t)MAXNC * sizeof(int), stream);

  dim3 blk(256);
  dim3 blk512(512);
  int gemmBlocks = (N + 127) / 128;
  int nodeBlocks = (N + 3) / 4;
  int chunkBlocks = (E + 4095) / 4096;

  // ---- weight prep ----
  wconv<<<16, blk, 0, stream>>>(W0, WtP0, 256);
  wconv<<<16, blk, 0, stream>>>(Wsk0, WtS0, 256);
  wconv<<<8, blk, 0, stream>>>(W2, WtP2, 128);
  wconv<<<8, blk, 0, stream>>>(Wsk2, WtS2, 128);

  // ---- CSR build (bucket counting sort) ----
  ccount<<<256, blk, 0, stream>>>(trg, bcnt, E, NC);
  cscan<<<1, blk, 0, stream>>>(bcnt, cbase, gcur, NC);
  cscatter<<<chunkBlocks, blk, 0, stream>>>(src, trg, gcur, EB, E, NC);
  bfill<<<NC, blk, 0, stream>>>(EB, cbase, rowptr, SS, N, E);

  // ---- layer 1 ----
  gemm_dual<256, true><<<gemmBlocks, blk512, 0, stream>>>(
      x, WtP0, WtS0, Sb, PH, a_src0, a_trg0, ssrc, strg, N);
  aggregate<1><<<nodeBlocks, blk, 0, stream>>>(rowptr, SS, (const float2*)ssrc,
                                               (const float2*)strg, PH, Sb, b0,
                                               Hb, N);
  // ---- layer 2 (h lives in Hb, bf16) ----
  gemm_dual<128, false><<<gemmBlocks, blk512, 0, stream>>>(
      Hb, WtP2, WtS2, Sb, PH, a_src2, a_trg2, ssrc, strg, N);
  aggregate<2><<<nodeBlocks, blk, 0, stream>>>(rowptr, SS, (const float2*)ssrc,
                                               (const float2*)strg, PH, Sb, b2,
                                               d_out, N);
}

// Round 14
// 180.339 us; speedup vs baseline: 1.1118x; 1.0110x over previous
//
#include <hip/hip_runtime.h>

#define NEG_SLOPE 0.2f
#define CBSH 7            // 128 nodes per coarse bucket
#define MAXNC 512         // max buckets (N <= 65536)

typedef __attribute__((ext_vector_type(8))) short short8;
typedef __attribute__((ext_vector_type(4))) float f32x4;

__device__ __forceinline__ unsigned short f2bf(float f) {
  unsigned u = __float_as_uint(f);
  unsigned r = (u + 0x7FFFu + ((u >> 16) & 1u)) >> 16;
  return (unsigned short)r;
}
__device__ __forceinline__ unsigned pack_bf16(float lo, float hi) {
  return (unsigned)f2bf(lo) | ((unsigned)f2bf(hi) << 16);
}
__device__ __forceinline__ float bflo(unsigned u) {
  return __uint_as_float(u << 16);
}
__device__ __forceinline__ float bfhi(unsigned u) {
  return __uint_as_float(u & 0xFFFF0000u);
}
__device__ __forceinline__ float rdlf(float v, int j) {
  return __uint_as_float(
      (unsigned)__builtin_amdgcn_readlane((int)__float_as_uint(v), j));
}
__device__ __forceinline__ void gload_lds16(const void* g, void* l) {
  __builtin_amdgcn_global_load_lds(
      (const __attribute__((address_space(1))) unsigned*)g,
      (__attribute__((address_space(3))) unsigned*)l, 16, 0, 0);
}

__global__ __launch_bounds__(256) void zerobuf(int* __restrict__ p, int n) {
  int i = blockIdx.x * 256 + threadIdx.x;
  if (i < n) p[i] = 0;
}

// ---------------------------------------------------------------------------
// W[K][128] fp32 -> Wt[128][K] bf16 (transpose+convert).
// ---------------------------------------------------------------------------
__global__ __launch_bounds__(256) void wconv(const float* __restrict__ W,
                                             unsigned* __restrict__ Wt, int K) {
  int per = K >> 3;
  int t = blockIdx.x * 256 + threadIdx.x;
  if (t >= 128 * per) return;
  int col = t / per;
  int kc = (t - col * per) << 3;
  float w[8];
#pragma unroll
  for (int j = 0; j < 8; ++j) w[j] = W[(size_t)(kc + j) * 128 + col];
  uint4 o = make_uint4(pack_bf16(w[0], w[1]), pack_bf16(w[2], w[3]),
                       pack_bf16(w[4], w[5]), pack_bf16(w[6], w[7]));
  *(uint4*)&Wt[((size_t)col * K + kc) >> 1] = o;
}

// ---------------------------------------------------------------------------
// CSR build, bucket counting-sort (write-combining friendly).
// ---------------------------------------------------------------------------
__global__ __launch_bounds__(256) void ccount(const int* __restrict__ trg,
                                              int* __restrict__ bcnt, int E,
                                              int NC) {
  __shared__ int hist[MAXNC];
  int tid = threadIdx.x;
  for (int i = tid; i < NC; i += 256) hist[i] = 0;
  __syncthreads();
  for (int e = blockIdx.x * 256 + tid; e < E; e += gridDim.x * 256)
    atomicAdd(&hist[trg[e] >> CBSH], 1);
  __syncthreads();
  for (int i = tid; i < NC; i += 256)
    if (hist[i]) atomicAdd(&bcnt[i], hist[i]);
}

__global__ __launch_bounds__(256) void cscan(const int* __restrict__ bcnt,
                                             int* __restrict__ cbase,
                                             int* __restrict__ gcur, int NC) {
  __shared__ int s[MAXNC + 1];
  int tid = threadIdx.x;
  for (int i = tid; i < NC; i += 256) s[i] = bcnt[i];
  __syncthreads();
  if (tid == 0) {
    int run = 0;
    for (int i = 0; i < NC; ++i) {
      int v = s[i];
      s[i] = run;
      run += v;
    }
    s[NC] = run;
  }
  __syncthreads();
  for (int i = tid; i <= NC; i += 256) cbase[i] = s[i];
  for (int i = tid; i < NC; i += 256) gcur[i] = s[i];
}

__global__ __launch_bounds__(256) void cscatter(const int* __restrict__ src,
                                                const int* __restrict__ trg,
                                                int* __restrict__ gcur,
                                                unsigned* __restrict__ EB,
                                                int E, int NC) {
  __shared__ int hist[MAXNC];
  __shared__ int gb[MAXNC];
  __shared__ int lcur[MAXNC];
  __shared__ unsigned lbuf[4096];
  __shared__ unsigned short cb16[4096];
  int tid = threadIdx.x;
  int e0 = blockIdx.x * 4096;
  int cnt = E - e0;
  if (cnt > 4096) cnt = 4096;
  for (int i = tid; i < NC; i += 256) hist[i] = 0;
  __syncthreads();
  unsigned pk[16];
  unsigned short cbr[16];
  int mine = 0;
#pragma unroll
  for (int j = 0; j < 16; ++j) {
    int i = tid + j * 256;
    if (i < cnt) {
      int e = e0 + i;
      int s = src[e];
      int t = trg[e];
      int cb = t >> CBSH;
      pk[j] = ((unsigned)s << CBSH) | (unsigned)(t & ((1 << CBSH) - 1));
      cbr[j] = (unsigned short)cb;
      atomicAdd(&hist[cb], 1);
      mine = j + 1;
    }
  }
  __syncthreads();
  for (int i = tid; i < NC; i += 256)
    gb[i] = hist[i] ? atomicAdd(&gcur[i], hist[i]) : 0;
  __syncthreads();
  if (tid == 0) {
    int run = 0;
    for (int i = 0; i < NC; ++i) {
      int v = hist[i];
      hist[i] = run;
      run += v;
    }
  }
  __syncthreads();
  for (int i = tid; i < NC; i += 256) lcur[i] = hist[i];
  __syncthreads();
  for (int j = 0; j < mine; ++j) {
    int p = atomicAdd(&lcur[cbr[j]], 1);
    lbuf[p] = pk[j];
    cb16[p] = cbr[j];
  }
  __syncthreads();
  for (int i = tid; i < cnt; i += 256) {
    int cb = cb16[i];
    EB[gb[cb] + (i - hist[cb])] = lbuf[i];
  }
}

__global__ __launch_bounds__(256) void bfill(const unsigned* __restrict__ EB,
                                             const int* __restrict__ cbase,
                                             int* __restrict__ rowptr,
                                             int* __restrict__ SS, int N,
                                             int E) {
  __shared__ int deg[128], lofs[128], cur[128];
  int cb = blockIdx.x;
  int b0 = cbase[cb];
  int b1 = cbase[cb + 1];
  int n0 = cb << CBSH;
  int tid = threadIdx.x;
  if (tid < 128) deg[tid] = 0;
  __syncthreads();
  for (int i = b0 + tid; i < b1; i += 256)
    atomicAdd(&deg[EB[i] & ((1 << CBSH) - 1)], 1);
  __syncthreads();
  if (tid == 0) {
    int run = b0;
    for (int l = 0; l < 128; ++l) {
      lofs[l] = run;
      run += deg[l];
    }
  }
  __syncthreads();
  if (tid < 128) {
    cur[tid] = lofs[tid];
    int n = n0 + tid;
    if (n < N) rowptr[n] = lofs[tid];
  }
  if (cb == 0 && tid == 0) rowptr[N] = E;
  __syncthreads();
  for (int i = b0 + tid; i < b1; i += 256) {
    unsigned pk = EB[i];
    int pos = atomicAdd(&cur[pk & ((1 << CBSH) - 1)], 1);
    SS[pos] = (int)(pk >> CBSH);
  }
}

// ---------------------------------------------------------------------------
// Fused dual bf16-MFMA GEMM — 128-row tile, 8 waves (512 thr), K_STEP=32
// (round-13, verified passing). LDS (33792 B): A-frags 8KB @0, BP @8192,
// BS @16384; epilogue Cs[64][132] aliases everything, two 64-row halves.
// ---------------------------------------------------------------------------
template <int KK, bool AF32>
__global__ __launch_bounds__(512) void gemm_dual(
    const void* __restrict__ Av, const unsigned* __restrict__ BtP,
    const unsigned* __restrict__ BtS, unsigned* __restrict__ Cb,
    unsigned* __restrict__ PH, const float* __restrict__ a_src,
    const float* __restrict__ a_trg, float* __restrict__ ssrc,
    float* __restrict__ strg, int M) {
  constexpr int NSTEP = KK / 32;
  __shared__ __align__(16) char ldsraw[33792];
  float(*Cs)[132] = (float(*)[132])ldsraw;

  const int tid = threadIdx.x;
  const int lane = tid & 63;
  const int w = tid >> 6;  // 0..7
  const int row0 = blockIdx.x * 128;

  f32x4 accP[8], accS[8];
#pragma unroll
  for (int c = 0; c < 8; ++c) {
    accP[c] = (f32x4)0.f;
    accS[c] = (f32x4)0.f;
  }

  const int arow = tid >> 2;
  const int akq = (tid & 3) << 3;
  const int agr = row0 + arow;
  const int abyte =
      ((((arow >> 4) << 6) | ((tid & 3) << 4) | (arow & 15)) << 4);
  const unsigned short* BP16 = (const unsigned short*)BtP;
  const unsigned short* BS16 = (const unsigned short*)BtS;
  const int bg = lane >> 4;
  const int br = lane & 15;

  for (int t = 0; t < NSTEP; ++t) {
    const int k0 = t << 5;
    {
      size_t eoff = (size_t)(16 * w + br) * KK + k0 + 8 * bg;
      gload_lds16(BP16 + eoff, ldsraw + 8192 + w * 1024);
      gload_lds16(BS16 + eoff, ldsraw + 16384 + w * 1024);
    }
    {
      uint4 p;
      if constexpr (AF32) {
        const float* A = (const float*)Av;
        float4 v0 = make_float4(0.f, 0.f, 0.f, 0.f), v1 = v0;
        if (agr < M) {
          v0 = *(const float4*)&A[(size_t)agr * KK + k0 + akq];
          v1 = *(const float4*)&A[(size_t)agr * KK + k0 + akq + 4];
        }
        p = make_uint4(pack_bf16(v0.x, v0.y), pack_bf16(v0.z, v0.w),
                       pack_bf16(v1.x, v1.y), pack_bf16(v1.z, v1.w));
      } else {
        const unsigned short* A = (const unsigned short*)Av;
        p = make_uint4(0u, 0u, 0u, 0u);
        if (agr < M) p = *(const uint4*)&A[(size_t)agr * KK + k0 + akq];
      }
      *(uint4*)(ldsraw + abyte) = p;
    }
    __syncthreads();
    short8 af = *(const short8*)(ldsraw + w * 1024 + lane * 16);
#pragma unroll
    for (int c = 0; c < 8; ++c) {
      short8 bp = *(const short8*)(ldsraw + 8192 + c * 1024 + lane * 16);
      accP[c] =
          __builtin_amdgcn_mfma_f32_16x16x32_bf16(af, bp, accP[c], 0, 0, 0);
      short8 bs = *(const short8*)(ldsraw + 16384 + c * 1024 + lane * 16);
      accS[c] =
          __builtin_amdgcn_mfma_f32_16x16x32_bf16(af, bs, accS[c], 0, 0, 0);
    }
    __syncthreads();
  }

  const int hrow = lane >> 5;
  const int c32 = lane & 31;
  const int wh = w >> 2;
  const int w4 = w & 3;

  // ---- proj epilogue (two 64-row halves): PH (bf16) + fused scores ----
#pragma unroll
  for (int h = 0; h < 2; ++h) {
    if (wh == h) {
#pragma unroll
      for (int c = 0; c < 8; ++c)
#pragma unroll
        for (int r = 0; r < 4; ++r)
          Cs[16 * w4 + ((lane >> 4) << 2) + r][16 * c + (lane & 15)] =
              accP[c][r];
    }
    __syncthreads();
    if (wh == h) {
#pragma unroll
      for (int i = 0; i < 8; ++i) {
        int lr = 16 * w4 + 2 * i + hrow;
        int gr = row0 + 64 * h + lr;
        if (gr < M) {
          float4 v = *(const float4*)&Cs[lr][c32 * 4];
          *(uint2*)&PH[(size_t)gr * 64 + c32 * 2] =
              make_uint2(pack_bf16(v.x, v.y), pack_bf16(v.z, v.w));
        }
      }
      int tid4 = tid - h * 256;
      int srow = tid4 >> 2;
      int q = tid4 & 3;
      int gr = row0 + 64 * h + srow;
      float ds = 0.f, dt = 0.f;
#pragma unroll
      for (int j = 0; j < 8; ++j) {
        int col = q * 32 + j * 4;
        float4 v = *(const float4*)&Cs[srow][col];
        float4 asv = *(const float4*)&a_src[col];
        float4 atv = *(const float4*)&a_trg[col];
        ds += v.x * asv.x + v.y * asv.y + v.z * asv.z + v.w * asv.w;
        dt += v.x * atv.x + v.y * atv.y + v.z * atv.z + v.w * atv.w;
      }
      ds += __shfl_xor(ds, 1, 64);
      dt += __shfl_xor(dt, 1, 64);
      if (gr < M && (q & 1) == 0) {
        int hh = q >> 1;
        ssrc[gr * 2 + hh] = ds;
        strg[gr * 2 + hh] = dt;
      }
    }
    __syncthreads();
  }

  // ---- skip epilogue (two halves): Cb (packed bf16) ----
#pragma unroll
  for (int h = 0; h < 2; ++h) {
    if (wh == h) {
#pragma unroll
      for (int c = 0; c < 8; ++c)
#pragma unroll
        for (int r = 0; r < 4; ++r)
          Cs[16 * w4 + ((lane >> 4) << 2) + r][16 * c + (lane & 15)] =
              accS[c][r];
    }
    __syncthreads();
    if (wh == h) {
#pragma unroll
      for (int i = 0; i < 8; ++i) {
        int lr = 16 * w4 + 2 * i + hrow;
        int gr = row0 + 64 * h + lr;
        if (gr < M) {
          float4 v = *(const float4*)&Cs[lr][c32 * 4];
          *(uint2*)&Cb[(size_t)gr * 64 + c32 * 2] =
              make_uint2(pack_bf16(v.x, v.y), pack_bf16(v.z, v.w));
        }
      }
    }
    __syncthreads();
  }
}

// ---------------------------------------------------------------------------
// Fused aggregation, VALU-lean: per 64-edge chunk, LANE j computes edge j's
// scores once (per-lane ssrc gather -> leaky -> exp for both heads); the
// per-edge inner loop broadcasts {index, g0, g1} via readlane (no trans, no
// broadcast loads) and does 1 PH gather + cndmask + 2 fma + dsum add.
// LAYER==1: out = packed-bf16 relu(agg+skip+b). LAYER==2: fp32 head-mean.
// ---------------------------------------------------------------------------
template <int LAYER>
__global__ __launch_bounds__(256) void aggregate(
    const int* __restrict__ rowptr, const int* __restrict__ SS,
    const float2* __restrict__ ssrc, const float2* __restrict__ strg,
    const unsigned* __restrict__ PH, const unsigned* __restrict__ Sb,
    const float* __restrict__ bias, void* __restrict__ Outv, int Nn) {
  int wid = (int)((blockIdx.x * blockDim.x + threadIdx.x) >> 6);
  int lane = threadIdx.x & 63;
  if (wid >= Nn) return;
  int n = wid;
  bool hi = lane >= 32;
  float2 st = strg[n];
  int beg = rowptr[n];
  int end = rowptr[n + 1];
  float accx = 0.f, accy = 0.f, dsum = 0.f;

  for (int base = beg; base < end; base += 64) {
    int cnt = end - base;
    if (cnt > 64) cnt = 64;
    int idx = base + lane;
    int sv = (idx < end) ? SS[idx] : 0;
    // lane j computes edge (base+j)'s exp-scores for both heads
    float2 es = ssrc[sv];
    float z0 = es.x + st.x;
    float z1 = es.y + st.y;
    z0 = (z0 >= 0.f) ? z0 : NEG_SLOPE * z0;
    z1 = (z1 >= 0.f) ? z1 : NEG_SLOPE * z1;
    float g0 = __expf(z0);
    float g1 = __expf(z1);
    int j = 0;
    for (; j + 4 <= cnt; j += 4) {
      int s0 = __builtin_amdgcn_readlane(sv, j + 0);
      int s1 = __builtin_amdgcn_readlane(sv, j + 1);
      int s2 = __builtin_amdgcn_readlane(sv, j + 2);
      int s3 = __builtin_amdgcn_readlane(sv, j + 3);
      unsigned w0 = PH[(size_t)s0 * 64 + lane];
      unsigned w1 = PH[(size_t)s1 * 64 + lane];
      unsigned w2 = PH[(size_t)s2 * 64 + lane];
      unsigned w3 = PH[(size_t)s3 * 64 + lane];
      float ga0 = rdlf(g0, j + 0), gb0 = rdlf(g1, j + 0);
      float ga1 = rdlf(g0, j + 1), gb1 = rdlf(g1, j + 1);
      float ga2 = rdlf(g0, j + 2), gb2 = rdlf(g1, j + 2);
      float ga3 = rdlf(g0, j + 3), gb3 = rdlf(g1, j + 3);
      float gh0 = hi ? gb0 : ga0;
      float gh1 = hi ? gb1 : ga1;
      float gh2 = hi ? gb2 : ga2;
      float gh3 = hi ? gb3 : ga3;
      dsum += (gh0 + gh1) + (gh2 + gh3);
      accx = fmaf(bflo(w0), gh0, accx);
      accy = fmaf(bfhi(w0), gh0, accy);
      accx = fmaf(bflo(w1), gh1, accx);
      accy = fmaf(bfhi(w1), gh1, accy);
      accx = fmaf(bflo(w2), gh2, accx);
      accy = fmaf(bfhi(w2), gh2, accy);
      accx = fmaf(bflo(w3), gh3, accx);
      accy = fmaf(bfhi(w3), gh3, accy);
    }
    for (; j < cnt; ++j) {
      int s0 = __builtin_amdgcn_readlane(sv, j);
      unsigned w0 = PH[(size_t)s0 * 64 + lane];
      float ga = rdlf(g0, j), gb = rdlf(g1, j);
      float gh = hi ? gb : ga;
      dsum += gh;
      accx = fmaf(bflo(w0), gh, accx);
      accy = fmaf(bfhi(w0), gh, accy);
    }
  }

  float inv = 1.0f / (dsum + 1e-16f);
  accx *= inv;
  accy *= inv;
  unsigned skv = Sb[(size_t)n * 64 + lane];
  float skx = bflo(skv);
  float sky = bfhi(skv);
  if (LAYER == 1) {
    float2 b = *(const float2*)&bias[lane * 2];
    float zx = fmaxf(accx + skx + b.x, 0.f);
    float zy = fmaxf(accy + sky + b.y, 0.f);
    ((unsigned*)Outv)[(size_t)n * 64 + lane] = pack_bf16(zx, zy);
  } else {
    float zx = accx + skx;
    float zy = accy + sky;
    float ox = __shfl(zx, lane + 32, 64);
    float oy = __shfl(zy, lane + 32, 64);
    if (lane < 32) {
      float2 b = *(const float2*)&bias[lane * 2];
      float rx = 0.5f * (zx + ox) + b.x;
      float ry = 0.5f * (zy + oy) + b.y;
      *(float2*)&((float*)Outv)[(size_t)n * 64 + lane * 2] =
          make_float2(rx, ry);
    }
  }
}

// ---------------------------------------------------------------------------
extern "C" void kernel_launch(void* const* d_in, const int* in_sizes, int n_in,
                              void* d_out, int out_size, void* d_ws,
                              size_t ws_size, hipStream_t stream) {
  const float* x = (const float*)d_in[0];
  const int* ei = (const int*)d_in[1];
  const float* W0 = (const float*)d_in[2];
  const float* a_src0 = (const float*)d_in[3];
  const float* a_trg0 = (const float*)d_in[4];
  const float* Wsk0 = (const float*)d_in[5];
  const float* b0 = (const float*)d_in[6];
  const float* W2 = (const float*)d_in[7];
  const float* a_src2 = (const float*)d_in[8];
  const float* a_trg2 = (const float*)d_in[9];
  const float* Wsk2 = (const float*)d_in[10];
  const float* b2 = (const float*)d_in[11];

  const int FIN = 256;
  const int N = in_sizes[0] / FIN;
  const int E = in_sizes[1] / 2;
  const int* src = ei;
  const int* trg = ei + E;
  const int NC = (N + (1 << CBSH) - 1) >> CBSH;

  char* base = (char*)d_ws;
  size_t off = 0;
  auto alloc = [&](size_t bytes) -> void* {
    void* p = base + off;
    off += (bytes + 255) & ~(size_t)255;
    return p;
  };
  unsigned* PH = (unsigned*)alloc((size_t)N * 64 * sizeof(unsigned));
  unsigned* Sb = (unsigned*)alloc((size_t)N * 64 * sizeof(unsigned));
  unsigned* Hb = (unsigned*)alloc((size_t)N * 64 * sizeof(unsigned));
  int* SS = (int*)alloc((size_t)E * sizeof(int));
  unsigned* EB = (unsigned*)alloc((size_t)E * sizeof(unsigned));
  float* ssrc = (float*)alloc((size_t)N * 2 * sizeof(float));
  float* strg = (float*)alloc((size_t)N * 2 * sizeof(float));
  int* rowptr = (int*)alloc((size_t)(N + 1) * sizeof(int));
  int* bcnt = (int*)alloc((size_t)MAXNC * sizeof(int));
  int* cbase = (int*)alloc((size_t)(MAXNC + 1) * sizeof(int));
  int* gcur = (int*)alloc((size_t)MAXNC * sizeof(int));
  unsigned* WtP0 = (unsigned*)alloc((size_t)128 * 256 * 2);
  unsigned* WtS0 = (unsigned*)alloc((size_t)128 * 256 * 2);
  unsigned* WtP2 = (unsigned*)alloc((size_t)128 * 128 * 2);
  unsigned* WtS2 = (unsigned*)alloc((size_t)128 * 128 * 2);

  dim3 blk(256);
  dim3 blk512(512);
  int gemmBlocks = (N + 127) / 128;
  int nodeBlocks = (N + 3) / 4;
  int chunkBlocks = (E + 4095) / 4096;

  zerobuf<<<2, blk, 0, stream>>>(bcnt, MAXNC);

  // ---- weight prep ----
  wconv<<<16, blk, 0, stream>>>(W0, WtP0, 256);
  wconv<<<16, blk, 0, stream>>>(Wsk0, WtS0, 256);
  wconv<<<8, blk, 0, stream>>>(W2, WtP2, 128);
  wconv<<<8, blk, 0, stream>>>(Wsk2, WtS2, 128);

  // ---- CSR build (bucket counting sort) ----
  ccount<<<256, blk, 0, stream>>>(trg, bcnt, E, NC);
  cscan<<<1, blk, 0, stream>>>(bcnt, cbase, gcur, NC);
  cscatter<<<chunkBlocks, blk, 0, stream>>>(src, trg, gcur, EB, E, NC);
  bfill<<<NC, blk, 0, stream>>>(EB, cbase, rowptr, SS, N, E);

  // ---- layer 1 ----
  gemm_dual<256, true><<<gemmBlocks, blk512, 0, stream>>>(
      x, WtP0, WtS0, Sb, PH, a_src0, a_trg0, ssrc, strg, N);
  aggregate<1><<<nodeBlocks, blk, 0, stream>>>(rowptr, SS, (const float2*)ssrc,
                                               (const float2*)strg, PH, Sb, b0,
                                               Hb, N);
  // ---- layer 2 (h lives in Hb, bf16) ----
  gemm_dual<128, false><<<gemmBlocks, blk512, 0, stream>>>(
      Hb, WtP2, WtS2, Sb, PH, a_src2, a_trg2, ssrc, strg, N);
  aggregate<2><<<nodeBlocks, blk, 0, stream>>>(rowptr, SS, (const float2*)ssrc,
                                               (const float2*)strg, PH, Sb, b2,
                                               d_out, N);
}

// Round 15
// 167.372 us; speedup vs baseline: 1.1980x; 1.0775x over previous
//
#include <hip/hip_runtime.h>

#define NEG_SLOPE 0.2f
#define CBSH 7            // 128 nodes per coarse bucket
#define MAXNC 512         // max buckets (N <= 65536)
#define BCAP 4096         // fixed per-bucket edge capacity (mean ~2046)

typedef __attribute__((ext_vector_type(8))) short short8;
typedef __attribute__((ext_vector_type(4))) float f32x4;

__device__ __forceinline__ unsigned short f2bf(float f) {
  unsigned u = __float_as_uint(f);
  unsigned r = (u + 0x7FFFu + ((u >> 16) & 1u)) >> 16;
  return (unsigned short)r;
}
__device__ __forceinline__ unsigned pack_bf16(float lo, float hi) {
  return (unsigned)f2bf(lo) | ((unsigned)f2bf(hi) << 16);
}
__device__ __forceinline__ float bflo(unsigned u) {
  return __uint_as_float(u << 16);
}
__device__ __forceinline__ float bfhi(unsigned u) {
  return __uint_as_float(u & 0xFFFF0000u);
}
__device__ __forceinline__ float rdlf(float v, int j) {
  return __uint_as_float(
      (unsigned)__builtin_amdgcn_readlane((int)__float_as_uint(v), j));
}
__device__ __forceinline__ void gload_lds16(const void* g, void* l) {
  __builtin_amdgcn_global_load_lds(
      (const __attribute__((address_space(1))) unsigned*)g,
      (__attribute__((address_space(3))) unsigned*)l, 16, 0, 0);
}

__global__ __launch_bounds__(256) void zerobuf(int* __restrict__ p, int n) {
  int i = blockIdx.x * 256 + threadIdx.x;
  if (i < n) p[i] = 0;
}

// ---------------------------------------------------------------------------
// W[K][128] fp32 -> Wt[128][K] bf16 (transpose+convert).
// ---------------------------------------------------------------------------
__global__ __launch_bounds__(256) void wconv(const float* __restrict__ W,
                                             unsigned* __restrict__ Wt, int K) {
  int per = K >> 3;
  int t = blockIdx.x * 256 + threadIdx.x;
  if (t >= 128 * per) return;
  int col = t / per;
  int kc = (t - col * per) << 3;
  float w[8];
#pragma unroll
  for (int j = 0; j < 8; ++j) w[j] = W[(size_t)(kc + j) * 128 + col];
  uint4 o = make_uint4(pack_bf16(w[0], w[1]), pack_bf16(w[2], w[3]),
                       pack_bf16(w[4], w[5]), pack_bf16(w[6], w[7]));
  *(uint4*)&Wt[((size_t)col * K + kc) >> 1] = o;
}

// ---------------------------------------------------------------------------
// CSR build, fixed-capacity bucket counting-sort (no global scan needed):
// cscatter (block-local sort + burst writes into cb*BCAP + reserved run)
// -> bfill (per-node degrees -> rowbeg/rowend + in-bucket scatter).
// ---------------------------------------------------------------------------
__global__ __launch_bounds__(256) void cscatter(const int* __restrict__ src,
                                                const int* __restrict__ trg,
                                                int* __restrict__ gcur,
                                                unsigned* __restrict__ EB,
                                                int E, int NC) {
  __shared__ int hist[MAXNC];
  __shared__ int gb[MAXNC];
  __shared__ int lcur[MAXNC];
  __shared__ unsigned lbuf[4096];
  __shared__ unsigned short cb16[4096];
  int tid = threadIdx.x;
  int e0 = blockIdx.x * 4096;
  int cnt = E - e0;
  if (cnt > 4096) cnt = 4096;
  for (int i = tid; i < NC; i += 256) hist[i] = 0;
  __syncthreads();
  unsigned pk[16];
  unsigned short cbr[16];
  int mine = 0;
#pragma unroll
  for (int j = 0; j < 16; ++j) {
    int i = tid + j * 256;
    if (i < cnt) {
      int e = e0 + i;
      int s = src[e];
      int t = trg[e];
      int cb = t >> CBSH;
      pk[j] = ((unsigned)s << CBSH) | (unsigned)(t & ((1 << CBSH) - 1));
      cbr[j] = (unsigned short)cb;
      atomicAdd(&hist[cb], 1);
      mine = j + 1;
    }
  }
  __syncthreads();
  for (int i = tid; i < NC; i += 256)
    gb[i] = hist[i] ? (i * BCAP + atomicAdd(&gcur[i], hist[i])) : 0;
  __syncthreads();
  if (tid == 0) {
    int run = 0;
    for (int i = 0; i < NC; ++i) {
      int v = hist[i];
      hist[i] = run;
      run += v;
    }
  }
  __syncthreads();
  for (int i = tid; i < NC; i += 256) lcur[i] = hist[i];
  __syncthreads();
  for (int j = 0; j < mine; ++j) {
    int p = atomicAdd(&lcur[cbr[j]], 1);
    lbuf[p] = pk[j];
    cb16[p] = cbr[j];
  }
  __syncthreads();
  for (int i = tid; i < cnt; i += 256) {
    int cb = cb16[i];
    EB[gb[cb] + (i - hist[cb])] = lbuf[i];
  }
}

// One block per bucket: per-node degrees -> rowbeg/rowend, in-bucket scatter.
__global__ __launch_bounds__(256) void bfill(const unsigned* __restrict__ EB,
                                             const int* __restrict__ gcur,
                                             int* __restrict__ rowbeg,
                                             int* __restrict__ rowend,
                                             int* __restrict__ SS, int N) {
  __shared__ int deg[128], lofs[128], cur[128];
  int cb = blockIdx.x;
  int b0 = cb * BCAP;
  int b1 = b0 + gcur[cb];
  int n0 = cb << CBSH;
  int tid = threadIdx.x;
  if (tid < 128) deg[tid] = 0;
  __syncthreads();
  for (int i = b0 + tid; i < b1; i += 256)
    atomicAdd(&deg[EB[i] & ((1 << CBSH) - 1)], 1);
  __syncthreads();
  if (tid == 0) {
    int run = b0;
    for (int l = 0; l < 128; ++l) {
      lofs[l] = run;
      run += deg[l];
    }
  }
  __syncthreads();
  if (tid < 128) {
    cur[tid] = lofs[tid];
    int n = n0 + tid;
    if (n < N) {
      rowbeg[n] = lofs[tid];
      rowend[n] = lofs[tid] + deg[tid];
    }
  }
  __syncthreads();
  for (int i = b0 + tid; i < b1; i += 256) {
    unsigned pk = EB[i];
    int pos = atomicAdd(&cur[pk & ((1 << CBSH) - 1)], 1);
    SS[pos] = (int)(pk >> CBSH);
  }
}

// ---------------------------------------------------------------------------
// Fused dual bf16-MFMA GEMM — 128-row tile, 8 waves (512 thr), K_STEP=32
// (round-13, verified passing). LDS (33792 B): A-frags 8KB @0, BP @8192,
// BS @16384; epilogue Cs[64][132] aliases everything, two 64-row halves.
// ---------------------------------------------------------------------------
template <int KK, bool AF32>
__global__ __launch_bounds__(512) void gemm_dual(
    const void* __restrict__ Av, const unsigned* __restrict__ BtP,
    const unsigned* __restrict__ BtS, unsigned* __restrict__ Cb,
    unsigned* __restrict__ PH, const float* __restrict__ a_src,
    const float* __restrict__ a_trg, float* __restrict__ ssrc,
    float* __restrict__ strg, int M) {
  constexpr int NSTEP = KK / 32;
  __shared__ __align__(16) char ldsraw[33792];
  float(*Cs)[132] = (float(*)[132])ldsraw;

  const int tid = threadIdx.x;
  const int lane = tid & 63;
  const int w = tid >> 6;  // 0..7
  const int row0 = blockIdx.x * 128;

  f32x4 accP[8], accS[8];
#pragma unroll
  for (int c = 0; c < 8; ++c) {
    accP[c] = (f32x4)0.f;
    accS[c] = (f32x4)0.f;
  }

  const int arow = tid >> 2;
  const int akq = (tid & 3) << 3;
  const int agr = row0 + arow;
  const int abyte =
      ((((arow >> 4) << 6) | ((tid & 3) << 4) | (arow & 15)) << 4);
  const unsigned short* BP16 = (const unsigned short*)BtP;
  const unsigned short* BS16 = (const unsigned short*)BtS;
  const int bg = lane >> 4;
  const int br = lane & 15;

  for (int t = 0; t < NSTEP; ++t) {
    const int k0 = t << 5;
    {
      size_t eoff = (size_t)(16 * w + br) * KK + k0 + 8 * bg;
      gload_lds16(BP16 + eoff, ldsraw + 8192 + w * 1024);
      gload_lds16(BS16 + eoff, ldsraw + 16384 + w * 1024);
    }
    {
      uint4 p;
      if constexpr (AF32) {
        const float* A = (const float*)Av;
        float4 v0 = make_float4(0.f, 0.f, 0.f, 0.f), v1 = v0;
        if (agr < M) {
          v0 = *(const float4*)&A[(size_t)agr * KK + k0 + akq];
          v1 = *(const float4*)&A[(size_t)agr * KK + k0 + akq + 4];
        }
        p = make_uint4(pack_bf16(v0.x, v0.y), pack_bf16(v0.z, v0.w),
                       pack_bf16(v1.x, v1.y), pack_bf16(v1.z, v1.w));
      } else {
        const unsigned short* A = (const unsigned short*)Av;
        p = make_uint4(0u, 0u, 0u, 0u);
        if (agr < M) p = *(const uint4*)&A[(size_t)agr * KK + k0 + akq];
      }
      *(uint4*)(ldsraw + abyte) = p;
    }
    __syncthreads();
    short8 af = *(const short8*)(ldsraw + w * 1024 + lane * 16);
#pragma unroll
    for (int c = 0; c < 8; ++c) {
      short8 bp = *(const short8*)(ldsraw + 8192 + c * 1024 + lane * 16);
      accP[c] =
          __builtin_amdgcn_mfma_f32_16x16x32_bf16(af, bp, accP[c], 0, 0, 0);
      short8 bs = *(const short8*)(ldsraw + 16384 + c * 1024 + lane * 16);
      accS[c] =
          __builtin_amdgcn_mfma_f32_16x16x32_bf16(af, bs, accS[c], 0, 0, 0);
    }
    __syncthreads();
  }

  const int hrow = lane >> 5;
  const int c32 = lane & 31;
  const int wh = w >> 2;
  const int w4 = w & 3;

  // ---- proj epilogue (two 64-row halves): PH (bf16) + fused scores ----
#pragma unroll
  for (int h = 0; h < 2; ++h) {
    if (wh == h) {
#pragma unroll
      for (int c = 0; c < 8; ++c)
#pragma unroll
        for (int r = 0; r < 4; ++r)
          Cs[16 * w4 + ((lane >> 4) << 2) + r][16 * c + (lane & 15)] =
              accP[c][r];
    }
    __syncthreads();
    if (wh == h) {
#pragma unroll
      for (int i = 0; i < 8; ++i) {
        int lr = 16 * w4 + 2 * i + hrow;
        int gr = row0 + 64 * h + lr;
        if (gr < M) {
          float4 v = *(const float4*)&Cs[lr][c32 * 4];
          *(uint2*)&PH[(size_t)gr * 64 + c32 * 2] =
              make_uint2(pack_bf16(v.x, v.y), pack_bf16(v.z, v.w));
        }
      }
      int tid4 = tid - h * 256;
      int srow = tid4 >> 2;
      int q = tid4 & 3;
      int gr = row0 + 64 * h + srow;
      float ds = 0.f, dt = 0.f;
#pragma unroll
      for (int j = 0; j < 8; ++j) {
        int col = q * 32 + j * 4;
        float4 v = *(const float4*)&Cs[srow][col];
        float4 asv = *(const float4*)&a_src[col];
        float4 atv = *(const float4*)&a_trg[col];
        ds += v.x * asv.x + v.y * asv.y + v.z * asv.z + v.w * asv.w;
        dt += v.x * atv.x + v.y * atv.y + v.z * atv.z + v.w * atv.w;
      }
      ds += __shfl_xor(ds, 1, 64);
      dt += __shfl_xor(dt, 1, 64);
      if (gr < M && (q & 1) == 0) {
        int hh = q >> 1;
        ssrc[gr * 2 + hh] = ds;
        strg[gr * 2 + hh] = dt;
      }
    }
    __syncthreads();
  }

  // ---- skip epilogue (two halves): Cb (packed bf16) ----
#pragma unroll
  for (int h = 0; h < 2; ++h) {
    if (wh == h) {
#pragma unroll
      for (int c = 0; c < 8; ++c)
#pragma unroll
        for (int r = 0; r < 4; ++r)
          Cs[16 * w4 + ((lane >> 4) << 2) + r][16 * c + (lane & 15)] =
              accS[c][r];
    }
    __syncthreads();
    if (wh == h) {
#pragma unroll
      for (int i = 0; i < 8; ++i) {
        int lr = 16 * w4 + 2 * i + hrow;
        int gr = row0 + 64 * h + lr;
        if (gr < M) {
          float4 v = *(const float4*)&Cs[lr][c32 * 4];
          *(uint2*)&Cb[(size_t)gr * 64 + c32 * 2] =
              make_uint2(pack_bf16(v.x, v.y), pack_bf16(v.z, v.w));
        }
      }
    }
    __syncthreads();
  }
}

// ---------------------------------------------------------------------------
// Fused aggregation, VALU-lean: lane j computes edge j's exp-scores once;
// denominator = wave-reduction of masked per-lane scores (hoisted out of the
// per-edge loop); per-edge work = readlane idx + 2 readlane g + cndmask +
// 1 PH gather + 2 unpack + 2 fma.
// LAYER==1: out = packed-bf16 relu(agg+skip+b). LAYER==2: fp32 head-mean.
// ---------------------------------------------------------------------------
template <int LAYER>
__global__ __launch_bounds__(256) void aggregate(
    const int* __restrict__ rowbeg, const int* __restrict__ rowend,
    const int* __restrict__ SS, const float2* __restrict__ ssrc,
    const float2* __restrict__ strg, const unsigned* __restrict__ PH,
    const unsigned* __restrict__ Sb, const float* __restrict__ bias,
    void* __restrict__ Outv, int Nn) {
  int wid = (int)((blockIdx.x * blockDim.x + threadIdx.x) >> 6);
  int lane = threadIdx.x & 63;
  if (wid >= Nn) return;
  int n = wid;
  bool hi = lane >= 32;
  float2 st = strg[n];
  int beg = rowbeg[n];
  int end = rowend[n];
  float accx = 0.f, accy = 0.f, dsum = 0.f;

  for (int base = beg; base < end; base += 64) {
    int cnt = end - base;
    if (cnt > 64) cnt = 64;
    int idx = base + lane;
    int sv = (idx < end) ? SS[idx] : 0;
    // lane j computes edge (base+j)'s exp-scores for both heads
    float2 es = ssrc[sv];
    float z0 = es.x + st.x;
    float z1 = es.y + st.y;
    z0 = (z0 >= 0.f) ? z0 : NEG_SLOPE * z0;
    z1 = (z1 >= 0.f) ? z1 : NEG_SLOPE * z1;
    float g0 = __expf(z0);
    float g1 = __expf(z1);
    if (idx >= end) {
      g0 = 0.f;
      g1 = 0.f;
    }
    // denominator: wave-sum of masked scores (replaces per-edge adds)
    {
      float s0 = g0, s1 = g1;
#pragma unroll
      for (int m = 1; m < 64; m <<= 1) {
        s0 += __shfl_xor(s0, m, 64);
        s1 += __shfl_xor(s1, m, 64);
      }
      dsum += hi ? s1 : s0;
    }
    int j = 0;
    for (; j + 4 <= cnt; j += 4) {
      int s0 = __builtin_amdgcn_readlane(sv, j + 0);
      int s1 = __builtin_amdgcn_readlane(sv, j + 1);
      int s2 = __builtin_amdgcn_readlane(sv, j + 2);
      int s3 = __builtin_amdgcn_readlane(sv, j + 3);
      unsigned w0 = PH[(size_t)s0 * 64 + lane];
      unsigned w1 = PH[(size_t)s1 * 64 + lane];
      unsigned w2 = PH[(size_t)s2 * 64 + lane];
      unsigned w3 = PH[(size_t)s3 * 64 + lane];
      float ga0 = rdlf(g0, j + 0), gb0 = rdlf(g1, j + 0);
      float ga1 = rdlf(g0, j + 1), gb1 = rdlf(g1, j + 1);
      float ga2 = rdlf(g0, j + 2), gb2 = rdlf(g1, j + 2);
      float ga3 = rdlf(g0, j + 3), gb3 = rdlf(g1, j + 3);
      float gh0 = hi ? gb0 : ga0;
      float gh1 = hi ? gb1 : ga1;
      float gh2 = hi ? gb2 : ga2;
      float gh3 = hi ? gb3 : ga3;
      accx = fmaf(bflo(w0), gh0, accx);
      accy = fmaf(bfhi(w0), gh0, accy);
      accx = fmaf(bflo(w1), gh1, accx);
      accy = fmaf(bfhi(w1), gh1, accy);
      accx = fmaf(bflo(w2), gh2, accx);
      accy = fmaf(bfhi(w2), gh2, accy);
      accx = fmaf(bflo(w3), gh3, accx);
      accy = fmaf(bfhi(w3), gh3, accy);
    }
    for (; j < cnt; ++j) {
      int s0 = __builtin_amdgcn_readlane(sv, j);
      unsigned w0 = PH[(size_t)s0 * 64 + lane];
      float ga = rdlf(g0, j), gb = rdlf(g1, j);
      float gh = hi ? gb : ga;
      accx = fmaf(bflo(w0), gh, accx);
      accy = fmaf(bfhi(w0), gh, accy);
    }
  }

  float inv = 1.0f / (dsum + 1e-16f);
  accx *= inv;
  accy *= inv;
  unsigned skv = Sb[(size_t)n * 64 + lane];
  float skx = bflo(skv);
  float sky = bfhi(skv);
  if (LAYER == 1) {
    float2 b = *(const float2*)&bias[lane * 2];
    float zx = fmaxf(accx + skx + b.x, 0.f);
    float zy = fmaxf(accy + sky + b.y, 0.f);
    ((unsigned*)Outv)[(size_t)n * 64 + lane] = pack_bf16(zx, zy);
  } else {
    float zx = accx + skx;
    float zy = accy + sky;
    float ox = __shfl(zx, lane + 32, 64);
    float oy = __shfl(zy, lane + 32, 64);
    if (lane < 32) {
      float2 b = *(const float2*)&bias[lane * 2];
      float rx = 0.5f * (zx + ox) + b.x;
      float ry = 0.5f * (zy + oy) + b.y;
      *(float2*)&((float*)Outv)[(size_t)n * 64 + lane * 2] =
          make_float2(rx, ry);
    }
  }
}

// ---------------------------------------------------------------------------
extern "C" void kernel_launch(void* const* d_in, const int* in_sizes, int n_in,
                              void* d_out, int out_size, void* d_ws,
                              size_t ws_size, hipStream_t stream) {
  const float* x = (const float*)d_in[0];
  const int* ei = (const int*)d_in[1];
  const float* W0 = (const float*)d_in[2];
  const float* a_src0 = (const float*)d_in[3];
  const float* a_trg0 = (const float*)d_in[4];
  const float* Wsk0 = (const float*)d_in[5];
  const float* b0 = (const float*)d_in[6];
  const float* W2 = (const float*)d_in[7];
  const float* a_src2 = (const float*)d_in[8];
  const float* a_trg2 = (const float*)d_in[9];
  const float* Wsk2 = (const float*)d_in[10];
  const float* b2 = (const float*)d_in[11];

  const int FIN = 256;
  const int N = in_sizes[0] / FIN;
  const int E = in_sizes[1] / 2;
  const int* src = ei;
  const int* trg = ei + E;
  const int NC = (N + (1 << CBSH) - 1) >> CBSH;

  char* base = (char*)d_ws;
  size_t off = 0;
  auto alloc = [&](size_t bytes) -> void* {
    void* p = base + off;
    off += (bytes + 255) & ~(size_t)255;
    return p;
  };
  unsigned* PH = (unsigned*)alloc((size_t)N * 64 * sizeof(unsigned));
  unsigned* Sb = (unsigned*)alloc((size_t)N * 64 * sizeof(unsigned));
  unsigned* Hb = (unsigned*)alloc((size_t)N * 64 * sizeof(unsigned));
  int* SS = (int*)alloc((size_t)NC * BCAP * sizeof(int));
  unsigned* EB = (unsigned*)alloc((size_t)NC * BCAP * sizeof(unsigned));
  float* ssrc = (float*)alloc((size_t)N * 2 * sizeof(float));
  float* strg = (float*)alloc((size_t)N * 2 * sizeof(float));
  int* rowbeg = (int*)alloc((size_t)N * sizeof(int));
  int* rowend = (int*)alloc((size_t)N * sizeof(int));
  int* gcur = (int*)alloc((size_t)MAXNC * sizeof(int));
  unsigned* WtP0 = (unsigned*)alloc((size_t)128 * 256 * 2);
  unsigned* WtS0 = (unsigned*)alloc((size_t)128 * 256 * 2);
  unsigned* WtP2 = (unsigned*)alloc((size_t)128 * 128 * 2);
  unsigned* WtS2 = (unsigned*)alloc((size_t)128 * 128 * 2);

  dim3 blk(256);
  dim3 blk512(512);
  int gemmBlocks = (N + 127) / 128;
  int nodeBlocks = (N + 3) / 4;
  int chunkBlocks = (E + 4095) / 4096;

  zerobuf<<<2, blk, 0, stream>>>(gcur, MAXNC);

  // ---- weight prep ----
  wconv<<<16, blk, 0, stream>>>(W0, WtP0, 256);
  wconv<<<16, blk, 0, stream>>>(Wsk0, WtS0, 256);
  wconv<<<8, blk, 0, stream>>>(W2, WtP2, 128);
  wconv<<<8, blk, 0, stream>>>(Wsk2, WtS2, 128);

  // ---- CSR build (fixed-capacity bucket counting sort) ----
  cscatter<<<chunkBlocks, blk, 0, stream>>>(src, trg, gcur, EB, E, NC);
  bfill<<<NC, blk, 0, stream>>>(EB, gcur, rowbeg, rowend, SS, N);

  // ---- layer 1 ----
  gemm_dual<256, true><<<gemmBlocks, blk512, 0, stream>>>(
      x, WtP0, WtS0, Sb, PH, a_src0, a_trg0, ssrc, strg, N);
  aggregate<1><<<nodeBlocks, blk, 0, stream>>>(
      rowbeg, rowend, SS, (const float2*)ssrc, (const float2*)strg, PH, Sb, b0,
      Hb, N);
  // ---- layer 2 (h lives in Hb, bf16) ----
  gemm_dual<128, false><<<gemmBlocks, blk512, 0, stream>>>(
      Hb, WtP2, WtS2, Sb, PH, a_src2, a_trg2, ssrc, strg, N);
  aggregate<2><<<nodeBlocks, blk, 0, stream>>>(
      rowbeg, rowend, SS, (const float2*)ssrc, (const float2*)strg, PH, Sb, b2,
      d_out, N);
}